// Round 1
// baseline (1351.703 us; speedup 1.0000x reference)
//
#include <hip/hip_runtime.h>

#define D_IN 384
#define HID 64
#define NLAYERS 3

// ---------------- input projection: h = relu(x @ W_in + b_in) ----------------
// Tiled f32 GEMM, M=N_nodes, K=384, N=64. Block computes 64 rows x 64 cols.
__global__ __launch_bounds__(256) void proj_kernel(const float* __restrict__ x,
                                                   const float* __restrict__ W,
                                                   const float* __restrict__ b,
                                                   float* __restrict__ h, int N) {
    __shared__ float As[64][33];   // 64 rows x 32 k (+1 pad)
    __shared__ float Bs[32][65];   // 32 k x 64 cols (+1 pad)
    const int m0 = blockIdx.x * 64;
    const int t  = threadIdx.x;
    const int tx = t & 15;         // col group (4 cols)
    const int ty = t >> 4;         // row group (4 rows)
    float acc[4][4] = {};

    for (int kc = 0; kc < D_IN; kc += 32) {
        #pragma unroll
        for (int i = 0; i < 8; i++) {            // A tile: 64x32
            int idx = t + i * 256;
            int r = idx >> 5, c = idx & 31;
            int row = m0 + r;
            As[r][c] = (row < N) ? x[(size_t)row * D_IN + kc + c] : 0.f;
        }
        #pragma unroll
        for (int i = 0; i < 8; i++) {            // B tile: 32x64
            int idx = t + i * 256;
            int r = idx >> 6, c = idx & 63;
            Bs[r][c] = W[(size_t)(kc + r) * HID + c];
        }
        __syncthreads();
        #pragma unroll
        for (int k = 0; k < 32; k++) {
            float a0 = As[ty*4+0][k], a1 = As[ty*4+1][k];
            float a2 = As[ty*4+2][k], a3 = As[ty*4+3][k];
            float b0 = Bs[k][tx*4+0], b1 = Bs[k][tx*4+1];
            float b2 = Bs[k][tx*4+2], b3 = Bs[k][tx*4+3];
            acc[0][0] += a0*b0; acc[0][1] += a0*b1; acc[0][2] += a0*b2; acc[0][3] += a0*b3;
            acc[1][0] += a1*b0; acc[1][1] += a1*b1; acc[1][2] += a1*b2; acc[1][3] += a1*b3;
            acc[2][0] += a2*b0; acc[2][1] += a2*b1; acc[2][2] += a2*b2; acc[2][3] += a2*b3;
            acc[3][0] += a3*b0; acc[3][1] += a3*b1; acc[3][2] += a3*b2; acc[3][3] += a3*b3;
        }
        __syncthreads();
    }
    #pragma unroll
    for (int i = 0; i < 4; i++) {
        int row = m0 + ty*4 + i;
        if (row < N) {
            #pragma unroll
            for (int j = 0; j < 4; j++) {
                int col = tx*4 + j;
                float v = acc[i][j] + b[col];
                h[(size_t)row * HID + col] = fmaxf(v, 0.f);
            }
        }
    }
}

// ---------------- CSR build ----------------
__global__ void count_kernel(const int* __restrict__ dst, int E, int* __restrict__ deg) {
    for (int e = blockIdx.x * blockDim.x + threadIdx.x; e < E; e += gridDim.x * blockDim.x)
        atomicAdd(&deg[dst[e]], 1);
}

// block-level exclusive scan, pass 1: per-block partials + block totals
__global__ void scan1(const int* __restrict__ deg, int N, int* __restrict__ part,
                      int* __restrict__ bsum) {
    __shared__ int s[256];
    int t = threadIdx.x;
    int g = blockIdx.x * 256 + t;
    int v = (g < N) ? deg[g] : 0;
    s[t] = v;
    __syncthreads();
    for (int o = 1; o < 256; o <<= 1) {
        int u = (t >= o) ? s[t - o] : 0;
        __syncthreads();
        s[t] += u;
        __syncthreads();
    }
    if (g < N) part[g] = s[t] - v;      // exclusive within block
    if (t == 255) bsum[blockIdx.x] = s[255];
}

// pass 2: exclusive scan of block totals (NB <= 512)
__global__ void scan2(int* __restrict__ bsum, int NB) {
    __shared__ int s[512];
    int t = threadIdx.x;
    int v = (t < NB) ? bsum[t] : 0;
    s[t] = v;
    __syncthreads();
    for (int o = 1; o < 512; o <<= 1) {
        int u = (t >= o) ? s[t - o] : 0;
        __syncthreads();
        s[t] += u;
        __syncthreads();
    }
    if (t < NB) bsum[t] = s[t] - v;
}

// pass 3: finalize offsets, init cursor, reciprocal clamped degree
__global__ void scan3(const int* __restrict__ bsum, const int* __restrict__ deg, int N,
                      int* __restrict__ offs, int* __restrict__ cursor,
                      float* __restrict__ rdeg) {
    int g = blockIdx.x * 256 + threadIdx.x;
    if (g < N) {
        int o = offs[g] + bsum[g >> 8];
        offs[g]   = o;
        cursor[g] = o;
        rdeg[g]   = 1.0f / (float)max(deg[g], 1);
        if (g == N - 1) offs[N] = o + deg[g];
    }
}

__global__ void fill_kernel(const int* __restrict__ src, const int* __restrict__ dst, int E,
                            int* __restrict__ cursor, int* __restrict__ ssorted) {
    for (int e = blockIdx.x * blockDim.x + threadIdx.x; e < E; e += gridDim.x * blockDim.x) {
        int p = atomicAdd(&cursor[dst[e]], 1);
        ssorted[p] = src[e];
    }
}

// ---------------- mean aggregation (gather over CSR) ----------------
// one wave (64 lanes) per node; lane = channel
__global__ __launch_bounds__(256) void agg_kernel(const float* __restrict__ h,
                                                  const int* __restrict__ offs,
                                                  const int* __restrict__ ssorted,
                                                  const float* __restrict__ rdeg,
                                                  float* __restrict__ agg, int N) {
    const int lane = threadIdx.x & 63;
    const int wid  = (blockIdx.x * blockDim.x + threadIdx.x) >> 6;
    const int nw   = (gridDim.x * blockDim.x) >> 6;
    for (int i = wid; i < N; i += nw) {
        int beg = offs[i], end = offs[i + 1];
        float acc = 0.f;
        for (int e = beg; e < end; e++) {
            int s = ssorted[e];
            acc += h[(size_t)s * HID + lane];
        }
        agg[(size_t)i * HID + lane] = acc * rdeg[i];
    }
}

// ---------------- fused SAGE layer ----------------
// out = agg@Wl + bl + h@Wr ; L2-normalize rows ; relu ; h' = LN(out + h)
__global__ __launch_bounds__(256) void layer_kernel(const float* __restrict__ hin,
                                                    const float* __restrict__ agg,
                                                    const float* __restrict__ Wl,
                                                    const float* __restrict__ Wr,
                                                    const float* __restrict__ bl,
                                                    const float* __restrict__ lng,
                                                    const float* __restrict__ lnb,
                                                    float* __restrict__ hout, int N) {
    __shared__ float sWl[HID * HID];
    __shared__ float sWr[HID * HID];
    for (int i = threadIdx.x; i < HID * HID; i += 256) {
        sWl[i] = Wl[i];
        sWr[i] = Wr[i];
    }
    __syncthreads();
    const int lane = threadIdx.x & 63;
    const int wid  = (blockIdx.x * blockDim.x + threadIdx.x) >> 6;
    const int nw   = (gridDim.x * blockDim.x) >> 6;
    const float blv  = bl[lane];
    const float gv   = lng[lane];
    const float bv   = lnb[lane];
    for (int i = wid; i < N; i += nw) {
        float a  = agg[(size_t)i * HID + lane];
        float hv = hin[(size_t)i * HID + lane];
        float out = blv;
        #pragma unroll
        for (int k = 0; k < HID; k++) {
            float ak = __shfl(a, k);
            float hk = __shfl(hv, k);
            out += ak * sWl[k * HID + lane] + hk * sWr[k * HID + lane];
        }
        // L2 normalize row
        float ss = out * out;
        #pragma unroll
        for (int o = 32; o > 0; o >>= 1) ss += __shfl_xor(ss, o);
        out *= rsqrtf(fmaxf(ss, 1e-24f));
        out = fmaxf(out, 0.f);
        // residual + layernorm
        float tv = out + hv;
        float m = tv;
        #pragma unroll
        for (int o = 32; o > 0; o >>= 1) m += __shfl_xor(m, o);
        m *= (1.f / 64.f);
        float d = tv - m;
        float vv = d * d;
        #pragma unroll
        for (int o = 32; o > 0; o >>= 1) vv += __shfl_xor(vv, o);
        vv *= (1.f / 64.f);
        hout[(size_t)i * HID + lane] = d * rsqrtf(vv + 1e-5f) * gv + bv;
    }
}

// ---------------- final layer norm (in-place safe) ----------------
__global__ __launch_bounds__(256) void final_ln(const float* __restrict__ hin,
                                                const float* __restrict__ g,
                                                const float* __restrict__ b,
                                                float* __restrict__ out, int N) {
    const int lane = threadIdx.x & 63;
    const int wid  = (blockIdx.x * blockDim.x + threadIdx.x) >> 6;
    const int nw   = (gridDim.x * blockDim.x) >> 6;
    const float gv = g[lane];
    const float bv = b[lane];
    for (int i = wid; i < N; i += nw) {
        float tv = hin[(size_t)i * HID + lane];
        float m = tv;
        #pragma unroll
        for (int o = 32; o > 0; o >>= 1) m += __shfl_xor(m, o);
        m *= (1.f / 64.f);
        float d = tv - m;
        float vv = d * d;
        #pragma unroll
        for (int o = 32; o > 0; o >>= 1) vv += __shfl_xor(vv, o);
        vv *= (1.f / 64.f);
        out[(size_t)i * HID + lane] = d * rsqrtf(vv + 1e-5f) * gv + bv;
    }
}

extern "C" void kernel_launch(void* const* d_in, const int* in_sizes, int n_in,
                              void* d_out, int out_size, void* d_ws, size_t ws_size,
                              hipStream_t stream) {
    const float* x     = (const float*)d_in[0];
    const int*   ei    = (const int*)d_in[1];
    const float* W_in  = (const float*)d_in[2];
    const float* b_in  = (const float*)d_in[3];
    const float* Wl    = (const float*)d_in[4];
    const float* bl    = (const float*)d_in[5];
    const float* Wr    = (const float*)d_in[6];
    const float* ln_g  = (const float*)d_in[7];
    const float* ln_b  = (const float*)d_in[8];
    const float* out_g = (const float*)d_in[9];
    const float* out_b = (const float*)d_in[10];

    const int N = in_sizes[0] / D_IN;
    const int E = in_sizes[1] / 2;
    const int* src = ei;
    const int* dst = ei + E;

    // workspace carve-up (256B aligned)
    char* ws = (char*)d_ws;
    size_t off = 0;
    auto take = [&](size_t bytes) {
        char* p = ws + off;
        off += (bytes + 255) & ~(size_t)255;
        return (void*)p;
    };
    float* h0      = (float*)take((size_t)N * HID * 4);
    float* aggb    = (float*)take((size_t)N * HID * 4);
    int*   deg     = (int*)take((size_t)N * 4);
    int*   offs    = (int*)take((size_t)(N + 1) * 4);
    int*   cursor  = (int*)take((size_t)N * 4);
    float* rdeg    = (float*)take((size_t)N * 4);
    int*   ssorted = (int*)take((size_t)E * 4);
    const int NB   = (N + 255) / 256;
    int*   bsum    = (int*)take((size_t)NB * 4);
    float* h1      = (float*)d_out;   // ping-pong through the output buffer

    // 1) input projection
    proj_kernel<<<(N + 63) / 64, 256, 0, stream>>>(x, W_in, b_in, h0, N);

    // 2) CSR build (by dst)
    hipMemsetAsync(deg, 0, (size_t)N * 4, stream);
    count_kernel<<<2048, 256, 0, stream>>>(dst, E, deg);
    scan1<<<NB, 256, 0, stream>>>(deg, N, offs, bsum);
    scan2<<<1, 512, 0, stream>>>(bsum, NB);
    scan3<<<NB, 256, 0, stream>>>(bsum, deg, N, offs, cursor, rdeg);
    fill_kernel<<<2048, 256, 0, stream>>>(src, dst, E, cursor, ssorted);

    // 3) layers (ping-pong h0 <-> d_out; ends with h in d_out after layer 3)
    float* hc = h0;
    float* hn = h1;
    for (int l = 0; l < NLAYERS; l++) {
        agg_kernel<<<2048, 256, 0, stream>>>(hc, offs, ssorted, rdeg, aggb, N);
        layer_kernel<<<2048, 256, 0, stream>>>(hc, aggb,
                                               Wl + (size_t)l * HID * HID,
                                               Wr + (size_t)l * HID * HID,
                                               bl + (size_t)l * HID,
                                               ln_g + (size_t)l * HID,
                                               ln_b + (size_t)l * HID, hn, N);
        float* tmp = hc; hc = hn; hn = tmp;
    }

    // 4) final layer norm (hc == d_out here; in-place per-row is safe)
    final_ln<<<2048, 256, 0, stream>>>(hc, out_g, out_b, (float*)d_out, N);
}

// Round 2
// 473.445 us; speedup vs baseline: 2.8550x; 2.8550x over previous
//
#include <hip/hip_runtime.h>

#define D_IN 384
#define HID 64
#define NLAYERS 3
#define KSTEPS_IN (D_IN / 32)   // 12

typedef __attribute__((ext_vector_type(8))) short bf16x8;
typedef __attribute__((ext_vector_type(4))) float f32x4;
typedef __attribute__((ext_vector_type(4))) unsigned short us4;
typedef unsigned short u16;

__device__ __forceinline__ u16 f2bf(float f) {
    union { float f; unsigned u; } v; v.f = f;
    unsigned u = v.u;
    return (u16)((u + 0x7fffu + ((u >> 16) & 1u)) >> 16);  // RNE
}
__device__ __forceinline__ float bf2f(u16 b) {
    union { unsigned u; float f; } v; v.u = ((unsigned)b) << 16;
    return v.f;
}

// ---------------- input projection: h = relu(x @ W_in + b_in), bf16 out ----------------
// Block: 256 threads = 4 waves; each wave computes 64 rows x 64 cols via MFMA 16x16x32.
__global__ __launch_bounds__(256) void proj_mfma(const float* __restrict__ x,
                                                 const float* __restrict__ W,
                                                 const float* __restrict__ b,
                                                 u16* __restrict__ h, int N) {
    __shared__ u16 sB[KSTEPS_IN * 4 * 64 * 8];   // fragment-ordered W, 48 KB
    const int t = threadIdx.x;
    const int lane = t & 63;
    const int w = t >> 6;

    // pack W fragments: frag (ks, ct), lane l holds B[k=ks*32+(l>>4)*8+i][col=ct*16+(l&15)]
    for (int fi = t; fi < KSTEPS_IN * 4 * 64; fi += 256) {
        int l  = fi & 63;
        int ct = (fi >> 6) & 3;
        int ks = fi >> 8;
        int kbase = ks * 32 + (l >> 4) * 8;
        int col   = ct * 16 + (l & 15);
        u16* d = &sB[(size_t)fi * 8];
        #pragma unroll
        for (int i = 0; i < 8; i++)
            d[i] = f2bf(W[(size_t)(kbase + i) * HID + col]);
    }
    __syncthreads();

    const int row0 = blockIdx.x * 256 + w * 64;
    f32x4 acc[4][4] = {};

    for (int ks = 0; ks < KSTEPS_IN; ks++) {
        bf16x8 a[4];
        #pragma unroll
        for (int rt = 0; rt < 4; rt++) {
            int row = row0 + rt * 16 + (lane & 15);
            if (row >= N) row = N - 1;
            const float* p = &x[(size_t)row * D_IN + ks * 32 + (lane >> 4) * 8];
            f32x4 x0 = *(const f32x4*)p;
            f32x4 x1 = *(const f32x4*)(p + 4);
            bf16x8 aa;
            aa[0] = (short)f2bf(x0[0]); aa[1] = (short)f2bf(x0[1]);
            aa[2] = (short)f2bf(x0[2]); aa[3] = (short)f2bf(x0[3]);
            aa[4] = (short)f2bf(x1[0]); aa[5] = (short)f2bf(x1[1]);
            aa[6] = (short)f2bf(x1[2]); aa[7] = (short)f2bf(x1[3]);
            a[rt] = aa;
        }
        #pragma unroll
        for (int ct = 0; ct < 4; ct++) {
            bf16x8 bb = *(const bf16x8*)&sB[(size_t)((ks * 4 + ct) * 64 + lane) * 8];
            #pragma unroll
            for (int rt = 0; rt < 4; rt++)
                acc[rt][ct] = __builtin_amdgcn_mfma_f32_16x16x32_bf16(a[rt], bb, acc[rt][ct], 0, 0, 0);
        }
    }

    float bias[4];
    #pragma unroll
    for (int ct = 0; ct < 4; ct++) bias[ct] = b[ct * 16 + (lane & 15)];

    #pragma unroll
    for (int rt = 0; rt < 4; rt++) {
        #pragma unroll
        for (int reg = 0; reg < 4; reg++) {
            int row = row0 + rt * 16 + (lane >> 4) * 4 + reg;
            if (row < N) {
                #pragma unroll
                for (int ct = 0; ct < 4; ct++) {
                    int col = ct * 16 + (lane & 15);
                    float v = acc[rt][ct][reg] + bias[ct];
                    h[(size_t)row * HID + col] = f2bf(fmaxf(v, 0.f));
                }
            }
        }
    }
}

// ---------------- CSR build ----------------
__global__ void count_kernel(const int* __restrict__ dst, int E, int* __restrict__ deg) {
    for (int e = blockIdx.x * blockDim.x + threadIdx.x; e < E; e += gridDim.x * blockDim.x)
        atomicAdd(&deg[dst[e]], 1);
}

__global__ void scan1(const int* __restrict__ deg, int N, int* __restrict__ part,
                      int* __restrict__ bsum) {
    __shared__ int s[256];
    int t = threadIdx.x;
    int g = blockIdx.x * 256 + t;
    int v = (g < N) ? deg[g] : 0;
    s[t] = v;
    __syncthreads();
    for (int o = 1; o < 256; o <<= 1) {
        int u = (t >= o) ? s[t - o] : 0;
        __syncthreads();
        s[t] += u;
        __syncthreads();
    }
    if (g < N) part[g] = s[t] - v;
    if (t == 255) bsum[blockIdx.x] = s[255];
}

__global__ void scan2(int* __restrict__ bsum, int NB) {
    __shared__ int s[512];
    int t = threadIdx.x;
    int v = (t < NB) ? bsum[t] : 0;
    s[t] = v;
    __syncthreads();
    for (int o = 1; o < 512; o <<= 1) {
        int u = (t >= o) ? s[t - o] : 0;
        __syncthreads();
        s[t] += u;
        __syncthreads();
    }
    if (t < NB) bsum[t] = s[t] - v;
}

__global__ void scan3(const int* __restrict__ bsum, const int* __restrict__ deg, int N,
                      int* __restrict__ offs, int* __restrict__ cursor,
                      float* __restrict__ rdeg) {
    int g = blockIdx.x * 256 + threadIdx.x;
    if (g < N) {
        int o = offs[g] + bsum[g >> 8];
        offs[g]   = o;
        cursor[g] = o;
        rdeg[g]   = 1.0f / (float)max(deg[g], 1);
        if (g == N - 1) offs[N] = o + deg[g];
    }
}

__global__ void fill_kernel(const int* __restrict__ src, const int* __restrict__ dst, int E,
                            int* __restrict__ cursor, int* __restrict__ ssorted) {
    for (int e = blockIdx.x * blockDim.x + threadIdx.x; e < E; e += gridDim.x * blockDim.x) {
        int p = atomicAdd(&cursor[dst[e]], 1);
        ssorted[p] = src[e];
    }
}

// ---------------- mean aggregation: gather bf16 rows, 4 edges in flight ----------------
// wave per node; 16-lane group g handles edges e+g; lane&15 -> channels (lane&15)*4..+3
__global__ __launch_bounds__(256) void agg_kernel(const u16* __restrict__ h,
                                                  const int* __restrict__ offs,
                                                  const int* __restrict__ ssorted,
                                                  const float* __restrict__ rdeg,
                                                  u16* __restrict__ agg, int N) {
    const int lane = threadIdx.x & 63;
    const int wid  = (blockIdx.x * blockDim.x + threadIdx.x) >> 6;
    const int nw   = (gridDim.x * blockDim.x) >> 6;
    const int sub  = lane >> 4;
    const int cg   = lane & 15;
    for (int i = wid; i < N; i += nw) {
        int beg = offs[i], end = offs[i + 1];
        float a0 = 0.f, a1 = 0.f, a2 = 0.f, a3 = 0.f;
        for (int e = beg + sub; e < end; e += 4) {
            int s = ssorted[e];
            us4 v = *(const us4*)&h[(size_t)s * HID + cg * 4];
            a0 += bf2f(v[0]); a1 += bf2f(v[1]); a2 += bf2f(v[2]); a3 += bf2f(v[3]);
        }
        #pragma unroll
        for (int m = 16; m < 64; m <<= 1) {
            a0 += __shfl_xor(a0, m);
            a1 += __shfl_xor(a1, m);
            a2 += __shfl_xor(a2, m);
            a3 += __shfl_xor(a3, m);
        }
        if (lane < 16) {
            float r = rdeg[i];
            us4 o;
            o[0] = f2bf(a0 * r); o[1] = f2bf(a1 * r);
            o[2] = f2bf(a2 * r); o[3] = f2bf(a3 * r);
            *(us4*)&agg[(size_t)i * HID + cg * 4] = o;
        }
    }
}

// ---------------- fused SAGE layer via MFMA ----------------
// out = [agg|h] @ [Wl;Wr] + bl ; L2-normalize ; relu ; h' = LN(out + h)
__global__ __launch_bounds__(256) void layer_mfma(const u16* __restrict__ hin,
                                                  const u16* __restrict__ agg,
                                                  const float* __restrict__ Wl,
                                                  const float* __restrict__ Wr,
                                                  const float* __restrict__ bl,
                                                  const float* __restrict__ lng,
                                                  const float* __restrict__ lnb,
                                                  u16* __restrict__ hout, int N) {
    __shared__ u16 sB[4 * 4 * 64 * 8];   // 16 KB fragment-ordered [Wl;Wr]
    const int t = threadIdx.x;
    const int lane = t & 63;
    const int w = t >> 6;

    for (int fi = t; fi < 4 * 4 * 64; fi += 256) {
        int l  = fi & 63;
        int ct = (fi >> 6) & 3;
        int ks = fi >> 8;
        int kbase = ks * 32 + (l >> 4) * 8;
        int col   = ct * 16 + (l & 15);
        u16* d = &sB[(size_t)fi * 8];
        #pragma unroll
        for (int i = 0; i < 8; i++) {
            int kk = kbase + i;
            float wv = (kk < 64) ? Wl[(size_t)kk * HID + col]
                                 : Wr[(size_t)(kk - 64) * HID + col];
            d[i] = f2bf(wv);
        }
    }
    __syncthreads();

    const int row0 = blockIdx.x * 256 + w * 64;
    f32x4 acc[4][4] = {};

    #pragma unroll
    for (int ks = 0; ks < 4; ks++) {
        const u16* srcp = (ks < 2) ? agg : hin;
        const int ch0 = (ks & 1) * 32 + (lane >> 4) * 8;
        bf16x8 a[4];
        #pragma unroll
        for (int rt = 0; rt < 4; rt++) {
            int row = row0 + rt * 16 + (lane & 15);
            if (row >= N) row = N - 1;
            a[rt] = *(const bf16x8*)&srcp[(size_t)row * HID + ch0];
        }
        #pragma unroll
        for (int ct = 0; ct < 4; ct++) {
            bf16x8 bb = *(const bf16x8*)&sB[(size_t)((ks * 4 + ct) * 64 + lane) * 8];
            #pragma unroll
            for (int rt = 0; rt < 4; rt++)
                acc[rt][ct] = __builtin_amdgcn_mfma_f32_16x16x32_bf16(a[rt], bb, acc[rt][ct], 0, 0, 0);
        }
    }

    float bias[4], g4[4], be4[4];
    #pragma unroll
    for (int ct = 0; ct < 4; ct++) {
        int c = ct * 16 + (lane & 15);
        bias[ct] = bl[c]; g4[ct] = lng[c]; be4[ct] = lnb[c];
    }

    #pragma unroll
    for (int rt = 0; rt < 4; rt++) {
        #pragma unroll
        for (int reg = 0; reg < 4; reg++) {
            int row = row0 + rt * 16 + (lane >> 4) * 4 + reg;   // uniform in 16-lane group
            if (row < N) {
                float v[4];
                float ss = 0.f;
                #pragma unroll
                for (int ct = 0; ct < 4; ct++) {
                    v[ct] = acc[rt][ct][reg] + bias[ct];
                    ss += v[ct] * v[ct];
                }
                #pragma unroll
                for (int m = 1; m < 16; m <<= 1) ss += __shfl_xor(ss, m);
                float rn = rsqrtf(fmaxf(ss, 1e-24f));
                float t4[4];
                float mean = 0.f;
                #pragma unroll
                for (int ct = 0; ct < 4; ct++) {
                    float o = fmaxf(v[ct] * rn, 0.f);
                    float hres = bf2f(hin[(size_t)row * HID + ct * 16 + (lane & 15)]);
                    t4[ct] = o + hres;
                    mean += t4[ct];
                }
                #pragma unroll
                for (int m = 1; m < 16; m <<= 1) mean += __shfl_xor(mean, m);
                mean *= (1.f / 64.f);
                float var = 0.f;
                #pragma unroll
                for (int ct = 0; ct < 4; ct++) {
                    float d = t4[ct] - mean;
                    var += d * d;
                }
                #pragma unroll
                for (int m = 1; m < 16; m <<= 1) var += __shfl_xor(var, m);
                var *= (1.f / 64.f);
                float rv = rsqrtf(var + 1e-5f);
                #pragma unroll
                for (int ct = 0; ct < 4; ct++)
                    hout[(size_t)row * HID + ct * 16 + (lane & 15)] =
                        f2bf((t4[ct] - mean) * rv * g4[ct] + be4[ct]);
            }
        }
    }
}

// ---------------- final layer norm: bf16 in, f32 out; 4 nodes per wave ----------------
__global__ __launch_bounds__(256) void final_ln(const u16* __restrict__ hin,
                                                const float* __restrict__ g,
                                                const float* __restrict__ b,
                                                float* __restrict__ out, int N) {
    const int lane = threadIdx.x & 63;
    const int wid  = (blockIdx.x * blockDim.x + threadIdx.x) >> 6;
    const int nw   = (gridDim.x * blockDim.x) >> 6;
    const int sub  = lane >> 4;
    const int cg   = lane & 15;
    f32x4 gv = *(const f32x4*)&g[cg * 4];
    f32x4 bv = *(const f32x4*)&b[cg * 4];
    for (int i0 = wid * 4; i0 < N; i0 += nw * 4) {
        int i = i0 + sub;
        if (i < N) {
            us4 hv = *(const us4*)&hin[(size_t)i * HID + cg * 4];
            float t0 = bf2f(hv[0]), t1 = bf2f(hv[1]), t2 = bf2f(hv[2]), t3 = bf2f(hv[3]);
            float mean = t0 + t1 + t2 + t3;
            #pragma unroll
            for (int m = 1; m < 16; m <<= 1) mean += __shfl_xor(mean, m);
            mean *= (1.f / 64.f);
            float d0 = t0 - mean, d1 = t1 - mean, d2 = t2 - mean, d3 = t3 - mean;
            float var = d0 * d0 + d1 * d1 + d2 * d2 + d3 * d3;
            #pragma unroll
            for (int m = 1; m < 16; m <<= 1) var += __shfl_xor(var, m);
            var *= (1.f / 64.f);
            float rv = rsqrtf(var + 1e-5f);
            f32x4 o;
            o[0] = d0 * rv * gv[0] + bv[0];
            o[1] = d1 * rv * gv[1] + bv[1];
            o[2] = d2 * rv * gv[2] + bv[2];
            o[3] = d3 * rv * gv[3] + bv[3];
            *(f32x4*)&out[(size_t)i * HID + cg * 4] = o;
        }
    }
}

extern "C" void kernel_launch(void* const* d_in, const int* in_sizes, int n_in,
                              void* d_out, int out_size, void* d_ws, size_t ws_size,
                              hipStream_t stream) {
    const float* x     = (const float*)d_in[0];
    const int*   ei    = (const int*)d_in[1];
    const float* W_in  = (const float*)d_in[2];
    const float* b_in  = (const float*)d_in[3];
    const float* Wl    = (const float*)d_in[4];
    const float* bl    = (const float*)d_in[5];
    const float* Wr    = (const float*)d_in[6];
    const float* ln_g  = (const float*)d_in[7];
    const float* ln_b  = (const float*)d_in[8];
    const float* out_g = (const float*)d_in[9];
    const float* out_b = (const float*)d_in[10];

    const int N = in_sizes[0] / D_IN;
    const int E = in_sizes[1] / 2;
    const int* src = ei;
    const int* dst = ei + E;

    char* ws = (char*)d_ws;
    size_t off = 0;
    auto take = [&](size_t bytes) {
        char* p = ws + off;
        off += (bytes + 255) & ~(size_t)255;
        return (void*)p;
    };
    u16*   h0      = (u16*)take((size_t)N * HID * 2);
    u16*   h1      = (u16*)take((size_t)N * HID * 2);
    u16*   aggb    = (u16*)take((size_t)N * HID * 2);
    int*   deg     = (int*)take((size_t)N * 4);
    int*   offs    = (int*)take((size_t)(N + 1) * 4);
    int*   cursor  = (int*)take((size_t)N * 4);
    float* rdeg    = (float*)take((size_t)N * 4);
    int*   ssorted = (int*)take((size_t)E * 4);
    const int NB   = (N + 255) / 256;
    int*   bsum    = (int*)take((size_t)NB * 4);

    const int NBLK = (N + 255) / 256;

    // 1) input projection (f32 x -> bf16 h)
    proj_mfma<<<NBLK, 256, 0, stream>>>(x, W_in, b_in, h0, N);

    // 2) CSR build (by dst)
    hipMemsetAsync(deg, 0, (size_t)N * 4, stream);
    count_kernel<<<2048, 256, 0, stream>>>(dst, E, deg);
    scan1<<<NB, 256, 0, stream>>>(deg, N, offs, bsum);
    scan2<<<1, 512, 0, stream>>>(bsum, NB);
    scan3<<<NB, 256, 0, stream>>>(bsum, deg, N, offs, cursor, rdeg);
    fill_kernel<<<2048, 256, 0, stream>>>(src, dst, E, cursor, ssorted);

    // 3) layers (ping-pong h0 <-> h1)
    u16* hc = h0;
    u16* hn = h1;
    for (int l = 0; l < NLAYERS; l++) {
        agg_kernel<<<2048, 256, 0, stream>>>(hc, offs, ssorted, rdeg, aggb, N);
        layer_mfma<<<NBLK, 256, 0, stream>>>(hc, aggb,
                                             Wl + (size_t)l * HID * HID,
                                             Wr + (size_t)l * HID * HID,
                                             bl + (size_t)l * HID,
                                             ln_g + (size_t)l * HID,
                                             ln_b + (size_t)l * HID, hn, N);
        u16* tmp = hc; hc = hn; hn = tmp;
    }

    // 4) final layer norm -> f32 output
    final_ln<<<2048, 256, 0, stream>>>(hc, out_g, out_b, (float*)d_out, N);
}

// Round 3
// 341.417 us; speedup vs baseline: 3.9591x; 1.3867x over previous
//
#include <hip/hip_runtime.h>

#define D_IN 384
#define HID 64
#define NLAYERS 3
#define KSTEPS_IN (D_IN / 32)   // 12
#define BKT_BITS 9
#define BKT_SIZE (1 << BKT_BITS)   // 512 nodes per bucket
#define CHUNK 4096                 // edges per phaseA block

typedef __attribute__((ext_vector_type(8))) short bf16x8;
typedef __attribute__((ext_vector_type(4))) float f32x4;
typedef __attribute__((ext_vector_type(4))) unsigned short us4;
typedef unsigned short u16;

__device__ __forceinline__ u16 f2bf(float f) {
    union { float f; unsigned u; } v; v.f = f;
    unsigned u = v.u;
    return (u16)((u + 0x7fffu + ((u >> 16) & 1u)) >> 16);  // RNE
}
__device__ __forceinline__ float bf2f(u16 b) {
    union { unsigned u; float f; } v; v.u = ((unsigned)b) << 16;
    return v.f;
}

// ---------------- input projection: h = relu(x @ W_in + b_in), bf16 out ----------------
__global__ __launch_bounds__(256) void proj_mfma(const float* __restrict__ x,
                                                 const float* __restrict__ W,
                                                 const float* __restrict__ b,
                                                 u16* __restrict__ h, int N) {
    __shared__ u16 sB[KSTEPS_IN * 4 * 64 * 8];   // fragment-ordered W, 48 KB
    const int t = threadIdx.x;
    const int lane = t & 63;
    const int w = t >> 6;

    for (int fi = t; fi < KSTEPS_IN * 4 * 64; fi += 256) {
        int l  = fi & 63;
        int ct = (fi >> 6) & 3;
        int ks = fi >> 8;
        int kbase = ks * 32 + (l >> 4) * 8;
        int col   = ct * 16 + (l & 15);
        u16* d = &sB[(size_t)fi * 8];
        #pragma unroll
        for (int i = 0; i < 8; i++)
            d[i] = f2bf(W[(size_t)(kbase + i) * HID + col]);
    }
    __syncthreads();

    const int row0 = blockIdx.x * 256 + w * 64;
    f32x4 acc[4][4] = {};

    for (int ks = 0; ks < KSTEPS_IN; ks++) {
        bf16x8 a[4];
        #pragma unroll
        for (int rt = 0; rt < 4; rt++) {
            int row = row0 + rt * 16 + (lane & 15);
            if (row >= N) row = N - 1;
            const float* p = &x[(size_t)row * D_IN + ks * 32 + (lane >> 4) * 8];
            f32x4 x0 = *(const f32x4*)p;
            f32x4 x1 = *(const f32x4*)(p + 4);
            bf16x8 aa;
            aa[0] = (short)f2bf(x0[0]); aa[1] = (short)f2bf(x0[1]);
            aa[2] = (short)f2bf(x0[2]); aa[3] = (short)f2bf(x0[3]);
            aa[4] = (short)f2bf(x1[0]); aa[5] = (short)f2bf(x1[1]);
            aa[6] = (short)f2bf(x1[2]); aa[7] = (short)f2bf(x1[3]);
            a[rt] = aa;
        }
        #pragma unroll
        for (int ct = 0; ct < 4; ct++) {
            bf16x8 bb = *(const bf16x8*)&sB[(size_t)((ks * 4 + ct) * 64 + lane) * 8];
            #pragma unroll
            for (int rt = 0; rt < 4; rt++)
                acc[rt][ct] = __builtin_amdgcn_mfma_f32_16x16x32_bf16(a[rt], bb, acc[rt][ct], 0, 0, 0);
        }
    }

    float bias[4];
    #pragma unroll
    for (int ct = 0; ct < 4; ct++) bias[ct] = b[ct * 16 + (lane & 15)];

    #pragma unroll
    for (int rt = 0; rt < 4; rt++) {
        #pragma unroll
        for (int reg = 0; reg < 4; reg++) {
            int row = row0 + rt * 16 + (lane >> 4) * 4 + reg;
            if (row < N) {
                #pragma unroll
                for (int ct = 0; ct < 4; ct++) {
                    int col = ct * 16 + (lane & 15);
                    float v = acc[rt][ct][reg] + bias[ct];
                    h[(size_t)row * HID + col] = f2bf(fmaxf(v, 0.f));
                }
            }
        }
    }
}

// ---------------- CSR build: two-phase LDS-binned counting sort ----------------
// requires nbuk <= 256 (N <= 131072)
__global__ __launch_bounds__(256) void bucket_count(const int* __restrict__ dst, int E,
                                                    int* __restrict__ bcnt, int nbuk) {
    __shared__ int hist[256];
    const int t = threadIdx.x;
    for (int i = t; i < nbuk; i += 256) hist[i] = 0;
    __syncthreads();
    for (int e = blockIdx.x * 256 + t; e < E; e += gridDim.x * 256)
        atomicAdd(&hist[dst[e] >> BKT_BITS], 1);
    __syncthreads();
    for (int i = t; i < nbuk; i += 256)
        if (hist[i]) atomicAdd(&bcnt[i], hist[i]);
}

__global__ void bucket_scan(const int* __restrict__ bcnt, int nbuk,
                            int* __restrict__ base, int* __restrict__ curA) {
    __shared__ int s[256];
    const int t = threadIdx.x;
    s[t] = (t < nbuk) ? bcnt[t] : 0;
    __syncthreads();
    for (int o = 1; o < 256; o <<= 1) {
        int v = (t >= o) ? s[t - o] : 0;
        __syncthreads();
        s[t] += v;
        __syncthreads();
    }
    // s is inclusive scan
    if (t <= nbuk) {
        int v = (t == 0) ? 0 : s[t - 1];
        base[t] = v;
        if (t < nbuk) curA[t] = v;
    }
}

// phase A: bin edges into buckets (packed src<<9 | dst&511), coalesced run writes
__global__ __launch_bounds__(256) void phaseA(const int* __restrict__ src,
                                              const int* __restrict__ dst, int E,
                                              int* __restrict__ curA,
                                              unsigned* __restrict__ packed, int nbuk) {
    __shared__ int hist[256];
    __shared__ int sc[256];
    __shared__ int lbase[256];
    __shared__ int gbase[256];
    __shared__ int lcur[256];
    __shared__ unsigned buf[CHUNK];
    __shared__ unsigned char bid[CHUNK];
    const int t = threadIdx.x;
    const int e0 = blockIdx.x * CHUNK;
    const int cnt = min(CHUNK, E - e0);

    if (t < nbuk) hist[t] = 0;
    __syncthreads();

    unsigned pk[CHUNK / 256];
    int bk[CHUNK / 256];
    #pragma unroll
    for (int j = 0; j < CHUNK / 256; j++) {
        int idx = j * 256 + t;
        if (idx < cnt) {
            int e = e0 + idx;
            int d = dst[e];
            int s = src[e];
            bk[j] = d >> BKT_BITS;
            pk[j] = ((unsigned)s << BKT_BITS) | (unsigned)(d & (BKT_SIZE - 1));
            atomicAdd(&hist[bk[j]], 1);
        } else bk[j] = -1;
    }
    __syncthreads();
    sc[t] = (t < nbuk) ? hist[t] : 0;
    __syncthreads();
    for (int o = 1; o < 256; o <<= 1) {
        int v = (t >= o) ? sc[t - o] : 0;
        __syncthreads();
        sc[t] += v;
        __syncthreads();
    }
    if (t < nbuk) {
        lbase[t] = sc[t] - hist[t];
        lcur[t] = 0;
        gbase[t] = hist[t] ? atomicAdd(&curA[t], hist[t]) : 0;
    }
    __syncthreads();
    #pragma unroll
    for (int j = 0; j < CHUNK / 256; j++) {
        if (bk[j] >= 0) {
            int r = atomicAdd(&lcur[bk[j]], 1);
            int slot = lbase[bk[j]] + r;
            buf[slot] = pk[j];
            bid[slot] = (unsigned char)bk[j];
        }
    }
    __syncthreads();
    for (int j = t; j < cnt; j += 256) {
        int b = bid[j];
        packed[gbase[b] + (j - lbase[b])] = buf[j];
    }
}

// phase B: per bucket, local deg/scan (-> offs, rdeg), then final placement
__global__ __launch_bounds__(256) void phaseB(const unsigned* __restrict__ packed,
                                              const int* __restrict__ base,
                                              int N, int E,
                                              int* __restrict__ ssorted,
                                              int* __restrict__ offs,
                                              float* __restrict__ rdeg) {
    __shared__ int ldeg[BKT_SIZE];
    __shared__ int s[BKT_SIZE];
    __shared__ int lcur[BKT_SIZE];
    const int b = blockIdx.x;
    const int t = threadIdx.x;
    const int beg = base[b], end = base[b + 1];
    for (int i = t; i < BKT_SIZE; i += 256) ldeg[i] = 0;
    __syncthreads();
    for (int j = beg + t; j < end; j += 256)
        atomicAdd(&ldeg[packed[j] & (BKT_SIZE - 1)], 1);
    __syncthreads();
    for (int i = t; i < BKT_SIZE; i += 256) s[i] = ldeg[i];
    __syncthreads();
    for (int o = 1; o < BKT_SIZE; o <<= 1) {
        int v0 = (t >= o) ? s[t - o] : 0;
        int i1 = t + 256;
        int v1 = (i1 >= o) ? s[i1 - o] : 0;
        __syncthreads();
        s[t] += v0;
        s[i1] += v1;
        __syncthreads();
    }
    const int n0 = b << BKT_BITS;
    for (int i = t; i < BKT_SIZE; i += 256) {
        int excl = (i == 0) ? 0 : s[i - 1];
        lcur[i] = excl;
        int n = n0 + i;
        if (n < N) {
            offs[n] = beg + excl;
            rdeg[n] = 1.0f / (float)max(ldeg[i], 1);
        }
    }
    if (b == 0 && t == 0) offs[N] = E;
    __syncthreads();
    for (int j = beg + t; j < end; j += 256) {
        unsigned p = packed[j];
        int l = p & (BKT_SIZE - 1);
        int r = atomicAdd(&lcur[l], 1);
        ssorted[beg + r] = (int)(p >> BKT_BITS);
    }
}

// ---------------- mean aggregation: gather bf16 rows ----------------
__global__ __launch_bounds__(256) void agg_kernel(const u16* __restrict__ h,
                                                  const int* __restrict__ offs,
                                                  const int* __restrict__ ssorted,
                                                  const float* __restrict__ rdeg,
                                                  u16* __restrict__ agg, int N) {
    const int lane = threadIdx.x & 63;
    const int wid  = (blockIdx.x * blockDim.x + threadIdx.x) >> 6;
    const int nw   = (gridDim.x * blockDim.x) >> 6;
    const int sub  = lane >> 4;
    const int cg   = lane & 15;
    for (int i = wid; i < N; i += nw) {
        int beg = offs[i], end = offs[i + 1];
        float a0 = 0.f, a1 = 0.f, a2 = 0.f, a3 = 0.f;
        for (int e = beg + sub; e < end; e += 4) {
            int s = ssorted[e];
            us4 v = *(const us4*)&h[(size_t)s * HID + cg * 4];
            a0 += bf2f(v[0]); a1 += bf2f(v[1]); a2 += bf2f(v[2]); a3 += bf2f(v[3]);
        }
        #pragma unroll
        for (int m = 16; m < 64; m <<= 1) {
            a0 += __shfl_xor(a0, m);
            a1 += __shfl_xor(a1, m);
            a2 += __shfl_xor(a2, m);
            a3 += __shfl_xor(a3, m);
        }
        if (lane < 16) {
            float r = rdeg[i];
            us4 o;
            o[0] = f2bf(a0 * r); o[1] = f2bf(a1 * r);
            o[2] = f2bf(a2 * r); o[3] = f2bf(a3 * r);
            *(us4*)&agg[(size_t)i * HID + cg * 4] = o;
        }
    }
}

// ---------------- fused SAGE layer via MFMA ----------------
__global__ __launch_bounds__(256) void layer_mfma(const u16* __restrict__ hin,
                                                  const u16* __restrict__ agg,
                                                  const float* __restrict__ Wl,
                                                  const float* __restrict__ Wr,
                                                  const float* __restrict__ bl,
                                                  const float* __restrict__ lng,
                                                  const float* __restrict__ lnb,
                                                  u16* __restrict__ hout, int N) {
    __shared__ u16 sB[4 * 4 * 64 * 8];
    const int t = threadIdx.x;
    const int lane = t & 63;
    const int w = t >> 6;

    for (int fi = t; fi < 4 * 4 * 64; fi += 256) {
        int l  = fi & 63;
        int ct = (fi >> 6) & 3;
        int ks = fi >> 8;
        int kbase = ks * 32 + (l >> 4) * 8;
        int col   = ct * 16 + (l & 15);
        u16* d = &sB[(size_t)fi * 8];
        #pragma unroll
        for (int i = 0; i < 8; i++) {
            int kk = kbase + i;
            float wv = (kk < 64) ? Wl[(size_t)kk * HID + col]
                                 : Wr[(size_t)(kk - 64) * HID + col];
            d[i] = f2bf(wv);
        }
    }
    __syncthreads();

    const int row0 = blockIdx.x * 256 + w * 64;
    f32x4 acc[4][4] = {};

    #pragma unroll
    for (int ks = 0; ks < 4; ks++) {
        const u16* srcp = (ks < 2) ? agg : hin;
        const int ch0 = (ks & 1) * 32 + (lane >> 4) * 8;
        bf16x8 a[4];
        #pragma unroll
        for (int rt = 0; rt < 4; rt++) {
            int row = row0 + rt * 16 + (lane & 15);
            if (row >= N) row = N - 1;
            a[rt] = *(const bf16x8*)&srcp[(size_t)row * HID + ch0];
        }
        #pragma unroll
        for (int ct = 0; ct < 4; ct++) {
            bf16x8 bb = *(const bf16x8*)&sB[(size_t)((ks * 4 + ct) * 64 + lane) * 8];
            #pragma unroll
            for (int rt = 0; rt < 4; rt++)
                acc[rt][ct] = __builtin_amdgcn_mfma_f32_16x16x32_bf16(a[rt], bb, acc[rt][ct], 0, 0, 0);
        }
    }

    float bias[4], g4[4], be4[4];
    #pragma unroll
    for (int ct = 0; ct < 4; ct++) {
        int c = ct * 16 + (lane & 15);
        bias[ct] = bl[c]; g4[ct] = lng[c]; be4[ct] = lnb[c];
    }

    #pragma unroll
    for (int rt = 0; rt < 4; rt++) {
        #pragma unroll
        for (int reg = 0; reg < 4; reg++) {
            int row = row0 + rt * 16 + (lane >> 4) * 4 + reg;
            if (row < N) {
                float v[4];
                float ss = 0.f;
                #pragma unroll
                for (int ct = 0; ct < 4; ct++) {
                    v[ct] = acc[rt][ct][reg] + bias[ct];
                    ss += v[ct] * v[ct];
                }
                #pragma unroll
                for (int m = 1; m < 16; m <<= 1) ss += __shfl_xor(ss, m);
                float rn = rsqrtf(fmaxf(ss, 1e-24f));
                float t4[4];
                float mean = 0.f;
                #pragma unroll
                for (int ct = 0; ct < 4; ct++) {
                    float o = fmaxf(v[ct] * rn, 0.f);
                    float hres = bf2f(hin[(size_t)row * HID + ct * 16 + (lane & 15)]);
                    t4[ct] = o + hres;
                    mean += t4[ct];
                }
                #pragma unroll
                for (int m = 1; m < 16; m <<= 1) mean += __shfl_xor(mean, m);
                mean *= (1.f / 64.f);
                float var = 0.f;
                #pragma unroll
                for (int ct = 0; ct < 4; ct++) {
                    float d = t4[ct] - mean;
                    var += d * d;
                }
                #pragma unroll
                for (int m = 1; m < 16; m <<= 1) var += __shfl_xor(var, m);
                var *= (1.f / 64.f);
                float rv = rsqrtf(var + 1e-5f);
                #pragma unroll
                for (int ct = 0; ct < 4; ct++)
                    hout[(size_t)row * HID + ct * 16 + (lane & 15)] =
                        f2bf((t4[ct] - mean) * rv * g4[ct] + be4[ct]);
            }
        }
    }
}

// ---------------- final layer norm: bf16 in, f32 out ----------------
__global__ __launch_bounds__(256) void final_ln(const u16* __restrict__ hin,
                                                const float* __restrict__ g,
                                                const float* __restrict__ b,
                                                float* __restrict__ out, int N) {
    const int lane = threadIdx.x & 63;
    const int wid  = (blockIdx.x * blockDim.x + threadIdx.x) >> 6;
    const int nw   = (gridDim.x * blockDim.x) >> 6;
    const int sub  = lane >> 4;
    const int cg   = lane & 15;
    f32x4 gv = *(const f32x4*)&g[cg * 4];
    f32x4 bv = *(const f32x4*)&b[cg * 4];
    for (int i0 = wid * 4; i0 < N; i0 += nw * 4) {
        int i = i0 + sub;
        if (i < N) {
            us4 hv = *(const us4*)&hin[(size_t)i * HID + cg * 4];
            float t0 = bf2f(hv[0]), t1 = bf2f(hv[1]), t2 = bf2f(hv[2]), t3 = bf2f(hv[3]);
            float mean = t0 + t1 + t2 + t3;
            #pragma unroll
            for (int m = 1; m < 16; m <<= 1) mean += __shfl_xor(mean, m);
            mean *= (1.f / 64.f);
            float d0 = t0 - mean, d1 = t1 - mean, d2 = t2 - mean, d3 = t3 - mean;
            float var = d0 * d0 + d1 * d1 + d2 * d2 + d3 * d3;
            #pragma unroll
            for (int m = 1; m < 16; m <<= 1) var += __shfl_xor(var, m);
            var *= (1.f / 64.f);
            float rv = rsqrtf(var + 1e-5f);
            f32x4 o;
            o[0] = d0 * rv * gv[0] + bv[0];
            o[1] = d1 * rv * gv[1] + bv[1];
            o[2] = d2 * rv * gv[2] + bv[2];
            o[3] = d3 * rv * gv[3] + bv[3];
            *(f32x4*)&out[(size_t)i * HID + cg * 4] = o;
        }
    }
}

extern "C" void kernel_launch(void* const* d_in, const int* in_sizes, int n_in,
                              void* d_out, int out_size, void* d_ws, size_t ws_size,
                              hipStream_t stream) {
    const float* x     = (const float*)d_in[0];
    const int*   ei    = (const int*)d_in[1];
    const float* W_in  = (const float*)d_in[2];
    const float* b_in  = (const float*)d_in[3];
    const float* Wl    = (const float*)d_in[4];
    const float* bl    = (const float*)d_in[5];
    const float* Wr    = (const float*)d_in[6];
    const float* ln_g  = (const float*)d_in[7];
    const float* ln_b  = (const float*)d_in[8];
    const float* out_g = (const float*)d_in[9];
    const float* out_b = (const float*)d_in[10];

    const int N = in_sizes[0] / D_IN;
    const int E = in_sizes[1] / 2;
    const int* src = ei;
    const int* dst = ei + E;
    const int nbuk = (N + BKT_SIZE - 1) >> BKT_BITS;   // 196, must be <= 256

    char* ws = (char*)d_ws;
    size_t off = 0;
    auto take = [&](size_t bytes) {
        char* p = ws + off;
        off += (bytes + 255) & ~(size_t)255;
        return (void*)p;
    };
    u16*      h0      = (u16*)take((size_t)N * HID * 2);
    u16*      h1      = (u16*)take((size_t)N * HID * 2);
    u16*      aggb    = (u16*)take((size_t)N * HID * 2);
    int*      offs    = (int*)take((size_t)(N + 1) * 4);
    float*    rdeg    = (float*)take((size_t)N * 4);
    int*      ssorted = (int*)take((size_t)E * 4);
    unsigned* packedA = (unsigned*)take((size_t)E * 4);
    int*      bcnt    = (int*)take((size_t)nbuk * 4);
    int*      base    = (int*)take((size_t)(nbuk + 1) * 4);
    int*      curA    = (int*)take((size_t)nbuk * 4);

    const int NBLK = (N + 255) / 256;

    // 1) input projection (f32 x -> bf16 h)
    proj_mfma<<<NBLK, 256, 0, stream>>>(x, W_in, b_in, h0, N);

    // 2) CSR build (two-phase binned counting sort)
    hipMemsetAsync(bcnt, 0, (size_t)nbuk * 4, stream);
    bucket_count<<<256, 256, 0, stream>>>(dst, E, bcnt, nbuk);
    bucket_scan<<<1, 256, 0, stream>>>(bcnt, nbuk, base, curA);
    phaseA<<<(E + CHUNK - 1) / CHUNK, 256, 0, stream>>>(src, dst, E, curA, packedA, nbuk);
    phaseB<<<nbuk, 256, 0, stream>>>(packedA, base, N, E, ssorted, offs, rdeg);

    // 3) layers (ping-pong h0 <-> h1)
    u16* hc = h0;
    u16* hn = h1;
    for (int l = 0; l < NLAYERS; l++) {
        agg_kernel<<<2048, 256, 0, stream>>>(hc, offs, ssorted, rdeg, aggb, N);
        layer_mfma<<<NBLK, 256, 0, stream>>>(hc, aggb,
                                             Wl + (size_t)l * HID * HID,
                                             Wr + (size_t)l * HID * HID,
                                             bl + (size_t)l * HID,
                                             ln_g + (size_t)l * HID,
                                             ln_b + (size_t)l * HID, hn, N);
        u16* tmp = hc; hc = hn; hn = tmp;
    }

    // 4) final layer norm -> f32 output
    final_ln<<<2048, 256, 0, stream>>>(hc, out_g, out_b, (float*)d_out, N);
}

// Round 4
// 284.007 us; speedup vs baseline: 4.7594x; 1.2021x over previous
//
#include <hip/hip_runtime.h>

#define D_IN 384
#define HID 64
#define NLAYERS 3
#define KSTEPS_IN (D_IN / 32)   // 12
#define BKT_BITS 9
#define BKT_SIZE (1 << BKT_BITS)   // 512 nodes per bucket
#define CHUNK 4096                 // edges per phaseA block

typedef __attribute__((ext_vector_type(8))) short bf16x8;
typedef __attribute__((ext_vector_type(4))) float f32x4;
typedef __attribute__((ext_vector_type(4))) unsigned short us4;
typedef unsigned short u16;

__device__ __forceinline__ u16 f2bf(float f) {
    union { float f; unsigned u; } v; v.f = f;
    unsigned u = v.u;
    return (u16)((u + 0x7fffu + ((u >> 16) & 1u)) >> 16);  // RNE
}
__device__ __forceinline__ float bf2f(u16 b) {
    union { unsigned u; float f; } v; v.u = ((unsigned)b) << 16;
    return v.f;
}

// ---------------- input projection: h = relu(x @ W_in + b_in), bf16 out ----------------
__global__ __launch_bounds__(256) void proj_mfma(const float* __restrict__ x,
                                                 const float* __restrict__ W,
                                                 const float* __restrict__ b,
                                                 u16* __restrict__ h, int N,
                                                 int* __restrict__ bcnt, int nbuk) {
    // stream-ordered zeroing of bucket counters (replaces hipMemsetAsync launch)
    if (blockIdx.x == 0 && threadIdx.x < (unsigned)nbuk) bcnt[threadIdx.x] = 0;

    __shared__ u16 sB[KSTEPS_IN * 4 * 64 * 8];   // fragment-ordered W, 48 KB
    const int t = threadIdx.x;
    const int lane = t & 63;
    const int w = t >> 6;

    for (int fi = t; fi < KSTEPS_IN * 4 * 64; fi += 256) {
        int l  = fi & 63;
        int ct = (fi >> 6) & 3;
        int ks = fi >> 8;
        int kbase = ks * 32 + (l >> 4) * 8;
        int col   = ct * 16 + (l & 15);
        u16* d = &sB[(size_t)fi * 8];
        #pragma unroll
        for (int i = 0; i < 8; i++)
            d[i] = f2bf(W[(size_t)(kbase + i) * HID + col]);
    }
    __syncthreads();

    const int row0 = blockIdx.x * 256 + w * 64;
    f32x4 acc[4][4] = {};

    for (int ks = 0; ks < KSTEPS_IN; ks++) {
        bf16x8 a[4];
        #pragma unroll
        for (int rt = 0; rt < 4; rt++) {
            int row = row0 + rt * 16 + (lane & 15);
            if (row >= N) row = N - 1;
            const float* p = &x[(size_t)row * D_IN + ks * 32 + (lane >> 4) * 8];
            f32x4 x0 = *(const f32x4*)p;
            f32x4 x1 = *(const f32x4*)(p + 4);
            bf16x8 aa;
            aa[0] = (short)f2bf(x0[0]); aa[1] = (short)f2bf(x0[1]);
            aa[2] = (short)f2bf(x0[2]); aa[3] = (short)f2bf(x0[3]);
            aa[4] = (short)f2bf(x1[0]); aa[5] = (short)f2bf(x1[1]);
            aa[6] = (short)f2bf(x1[2]); aa[7] = (short)f2bf(x1[3]);
            a[rt] = aa;
        }
        #pragma unroll
        for (int ct = 0; ct < 4; ct++) {
            bf16x8 bb = *(const bf16x8*)&sB[(size_t)((ks * 4 + ct) * 64 + lane) * 8];
            #pragma unroll
            for (int rt = 0; rt < 4; rt++)
                acc[rt][ct] = __builtin_amdgcn_mfma_f32_16x16x32_bf16(a[rt], bb, acc[rt][ct], 0, 0, 0);
        }
    }

    float bias[4];
    #pragma unroll
    for (int ct = 0; ct < 4; ct++) bias[ct] = b[ct * 16 + (lane & 15)];

    #pragma unroll
    for (int rt = 0; rt < 4; rt++) {
        #pragma unroll
        for (int reg = 0; reg < 4; reg++) {
            int row = row0 + rt * 16 + (lane >> 4) * 4 + reg;
            if (row < N) {
                #pragma unroll
                for (int ct = 0; ct < 4; ct++) {
                    int col = ct * 16 + (lane & 15);
                    float v = acc[rt][ct][reg] + bias[ct];
                    h[(size_t)row * HID + col] = f2bf(fmaxf(v, 0.f));
                }
            }
        }
    }
}

// ---------------- CSR build: two-phase LDS-binned counting sort ----------------
__global__ __launch_bounds__(256) void bucket_count(const int* __restrict__ dst, int E,
                                                    int* __restrict__ bcnt, int nbuk) {
    __shared__ int hist[256];
    const int t = threadIdx.x;
    for (int i = t; i < nbuk; i += 256) hist[i] = 0;
    __syncthreads();
    for (int e = blockIdx.x * 256 + t; e < E; e += gridDim.x * 256)
        atomicAdd(&hist[dst[e] >> BKT_BITS], 1);
    __syncthreads();
    for (int i = t; i < nbuk; i += 256)
        if (hist[i]) atomicAdd(&bcnt[i], hist[i]);
}

__global__ void bucket_scan(const int* __restrict__ bcnt, int nbuk,
                            int* __restrict__ base, int* __restrict__ curA) {
    __shared__ int s[256];
    const int t = threadIdx.x;
    s[t] = (t < nbuk) ? bcnt[t] : 0;
    __syncthreads();
    for (int o = 1; o < 256; o <<= 1) {
        int v = (t >= o) ? s[t - o] : 0;
        __syncthreads();
        s[t] += v;
        __syncthreads();
    }
    if (t <= nbuk) {
        int v = (t == 0) ? 0 : s[t - 1];
        base[t] = v;
        if (t < nbuk) curA[t] = v;
    }
}

__global__ __launch_bounds__(256) void phaseA(const int* __restrict__ src,
                                              const int* __restrict__ dst, int E,
                                              int* __restrict__ curA,
                                              unsigned* __restrict__ packed, int nbuk) {
    __shared__ int hist[256];
    __shared__ int sc[256];
    __shared__ int lbase[256];
    __shared__ int gbase[256];
    __shared__ int lcur[256];
    __shared__ unsigned buf[CHUNK];
    __shared__ unsigned char bid[CHUNK];
    const int t = threadIdx.x;
    const int e0 = blockIdx.x * CHUNK;
    const int cnt = min(CHUNK, E - e0);

    if (t < nbuk) hist[t] = 0;
    __syncthreads();

    unsigned pk[CHUNK / 256];
    int bk[CHUNK / 256];
    #pragma unroll
    for (int j = 0; j < CHUNK / 256; j++) {
        int idx = j * 256 + t;
        if (idx < cnt) {
            int e = e0 + idx;
            int d = dst[e];
            int s = src[e];
            bk[j] = d >> BKT_BITS;
            pk[j] = ((unsigned)s << BKT_BITS) | (unsigned)(d & (BKT_SIZE - 1));
            atomicAdd(&hist[bk[j]], 1);
        } else bk[j] = -1;
    }
    __syncthreads();
    sc[t] = (t < nbuk) ? hist[t] : 0;
    __syncthreads();
    for (int o = 1; o < 256; o <<= 1) {
        int v = (t >= o) ? sc[t - o] : 0;
        __syncthreads();
        sc[t] += v;
        __syncthreads();
    }
    if (t < nbuk) {
        lbase[t] = sc[t] - hist[t];
        lcur[t] = 0;
        gbase[t] = hist[t] ? atomicAdd(&curA[t], hist[t]) : 0;
    }
    __syncthreads();
    #pragma unroll
    for (int j = 0; j < CHUNK / 256; j++) {
        if (bk[j] >= 0) {
            int r = atomicAdd(&lcur[bk[j]], 1);
            int slot = lbase[bk[j]] + r;
            buf[slot] = pk[j];
            bid[slot] = (unsigned char)bk[j];
        }
    }
    __syncthreads();
    for (int j = t; j < cnt; j += 256) {
        int b = bid[j];
        packed[gbase[b] + (j - lbase[b])] = buf[j];
    }
}

__global__ __launch_bounds__(256) void phaseB(const unsigned* __restrict__ packed,
                                              const int* __restrict__ base,
                                              int N, int E,
                                              int* __restrict__ ssorted,
                                              int* __restrict__ offs,
                                              float* __restrict__ rdeg) {
    __shared__ int ldeg[BKT_SIZE];
    __shared__ int s[BKT_SIZE];
    __shared__ int lcur[BKT_SIZE];
    const int b = blockIdx.x;
    const int t = threadIdx.x;
    const int beg = base[b], end = base[b + 1];
    for (int i = t; i < BKT_SIZE; i += 256) ldeg[i] = 0;
    __syncthreads();
    for (int j = beg + t; j < end; j += 256)
        atomicAdd(&ldeg[packed[j] & (BKT_SIZE - 1)], 1);
    __syncthreads();
    for (int i = t; i < BKT_SIZE; i += 256) s[i] = ldeg[i];
    __syncthreads();
    for (int o = 1; o < BKT_SIZE; o <<= 1) {
        int v0 = (t >= o) ? s[t - o] : 0;
        int i1 = t + 256;
        int v1 = (i1 >= o) ? s[i1 - o] : 0;
        __syncthreads();
        s[t] += v0;
        s[i1] += v1;
        __syncthreads();
    }
    const int n0 = b << BKT_BITS;
    for (int i = t; i < BKT_SIZE; i += 256) {
        int excl = (i == 0) ? 0 : s[i - 1];
        lcur[i] = excl;
        int n = n0 + i;
        if (n < N) {
            offs[n] = beg + excl;
            rdeg[n] = 1.0f / (float)max(ldeg[i], 1);
        }
    }
    if (b == 0 && t == 0) offs[N] = E;
    __syncthreads();
    for (int j = beg + t; j < end; j += 256) {
        unsigned p = packed[j];
        int l = p & (BKT_SIZE - 1);
        int r = atomicAdd(&lcur[l], 1);
        ssorted[beg + r] = (int)(p >> BKT_BITS);
    }
}

// ---------------- mean aggregation: 4-way unrolled gathers (MLP=4) ----------------
// wave per node; subgroup sub (0..3) handles edges e0+sub, +4, +8, +12; cg = channel group
__global__ __launch_bounds__(256) void agg_kernel(const u16* __restrict__ h,
                                                  const int* __restrict__ offs,
                                                  const int* __restrict__ ssorted,
                                                  const float* __restrict__ rdeg,
                                                  u16* __restrict__ agg, int N) {
    const int lane = threadIdx.x & 63;
    const int wid  = (blockIdx.x * blockDim.x + threadIdx.x) >> 6;
    const int nw   = (gridDim.x * blockDim.x) >> 6;
    const int sub  = lane >> 4;
    const int cg   = lane & 15;
    for (int i = wid; i < N; i += nw) {
        int beg = offs[i], end = offs[i + 1];
        float a0 = 0.f, a1 = 0.f, a2 = 0.f, a3 = 0.f;
        for (int e0 = beg; e0 < end; e0 += 16) {
            int e = e0 + sub;
            int j0 = e, j1 = e + 4, j2 = e + 8, j3 = e + 12;
            float p0 = (j0 < end) ? 1.f : 0.f;
            float p1 = (j1 < end) ? 1.f : 0.f;
            float p2 = (j2 < end) ? 1.f : 0.f;
            float p3 = (j3 < end) ? 1.f : 0.f;
            j0 = min(j0, end - 1); j1 = min(j1, end - 1);
            j2 = min(j2, end - 1); j3 = min(j3, end - 1);
            int s0 = ssorted[j0], s1 = ssorted[j1], s2 = ssorted[j2], s3 = ssorted[j3];
            us4 v0 = *(const us4*)&h[(size_t)s0 * HID + cg * 4];
            us4 v1 = *(const us4*)&h[(size_t)s1 * HID + cg * 4];
            us4 v2 = *(const us4*)&h[(size_t)s2 * HID + cg * 4];
            us4 v3 = *(const us4*)&h[(size_t)s3 * HID + cg * 4];
            a0 += p0 * bf2f(v0[0]) + p1 * bf2f(v1[0]) + p2 * bf2f(v2[0]) + p3 * bf2f(v3[0]);
            a1 += p0 * bf2f(v0[1]) + p1 * bf2f(v1[1]) + p2 * bf2f(v2[1]) + p3 * bf2f(v3[1]);
            a2 += p0 * bf2f(v0[2]) + p1 * bf2f(v1[2]) + p2 * bf2f(v2[2]) + p3 * bf2f(v3[2]);
            a3 += p0 * bf2f(v0[3]) + p1 * bf2f(v1[3]) + p2 * bf2f(v2[3]) + p3 * bf2f(v3[3]);
        }
        #pragma unroll
        for (int m = 16; m < 64; m <<= 1) {
            a0 += __shfl_xor(a0, m);
            a1 += __shfl_xor(a1, m);
            a2 += __shfl_xor(a2, m);
            a3 += __shfl_xor(a3, m);
        }
        if (lane < 16) {
            float r = rdeg[i];
            us4 o;
            o[0] = f2bf(a0 * r); o[1] = f2bf(a1 * r);
            o[2] = f2bf(a2 * r); o[3] = f2bf(a3 * r);
            *(us4*)&agg[(size_t)i * HID + cg * 4] = o;
        }
    }
}

// ---------------- fused SAGE layer via MFMA (LAST also applies output LN -> f32) ----
template<bool LAST>
__global__ __launch_bounds__(256) void layer_mfma(const u16* __restrict__ hin,
                                                  const u16* __restrict__ agg,
                                                  const float* __restrict__ Wl,
                                                  const float* __restrict__ Wr,
                                                  const float* __restrict__ bl,
                                                  const float* __restrict__ lng,
                                                  const float* __restrict__ lnb,
                                                  const float* __restrict__ og,
                                                  const float* __restrict__ ob,
                                                  u16* __restrict__ hout,
                                                  float* __restrict__ fout, int N) {
    __shared__ u16 sB[4 * 4 * 64 * 8];
    const int t = threadIdx.x;
    const int lane = t & 63;
    const int w = t >> 6;

    for (int fi = t; fi < 4 * 4 * 64; fi += 256) {
        int l  = fi & 63;
        int ct = (fi >> 6) & 3;
        int ks = fi >> 8;
        int kbase = ks * 32 + (l >> 4) * 8;
        int col   = ct * 16 + (l & 15);
        u16* d = &sB[(size_t)fi * 8];
        #pragma unroll
        for (int i = 0; i < 8; i++) {
            int kk = kbase + i;
            float wv = (kk < 64) ? Wl[(size_t)kk * HID + col]
                                 : Wr[(size_t)(kk - 64) * HID + col];
            d[i] = f2bf(wv);
        }
    }
    __syncthreads();

    const int row0 = blockIdx.x * 256 + w * 64;
    f32x4 acc[4][4] = {};

    #pragma unroll
    for (int ks = 0; ks < 4; ks++) {
        const u16* srcp = (ks < 2) ? agg : hin;
        const int ch0 = (ks & 1) * 32 + (lane >> 4) * 8;
        bf16x8 a[4];
        #pragma unroll
        for (int rt = 0; rt < 4; rt++) {
            int row = row0 + rt * 16 + (lane & 15);
            if (row >= N) row = N - 1;
            a[rt] = *(const bf16x8*)&srcp[(size_t)row * HID + ch0];
        }
        #pragma unroll
        for (int ct = 0; ct < 4; ct++) {
            bf16x8 bb = *(const bf16x8*)&sB[(size_t)((ks * 4 + ct) * 64 + lane) * 8];
            #pragma unroll
            for (int rt = 0; rt < 4; rt++)
                acc[rt][ct] = __builtin_amdgcn_mfma_f32_16x16x32_bf16(a[rt], bb, acc[rt][ct], 0, 0, 0);
        }
    }

    float bias[4], g4[4], be4[4], og4[4], ob4[4];
    #pragma unroll
    for (int ct = 0; ct < 4; ct++) {
        int c = ct * 16 + (lane & 15);
        bias[ct] = bl[c]; g4[ct] = lng[c]; be4[ct] = lnb[c];
        if (LAST) { og4[ct] = og[c]; ob4[ct] = ob[c]; }
    }

    #pragma unroll
    for (int rt = 0; rt < 4; rt++) {
        #pragma unroll
        for (int reg = 0; reg < 4; reg++) {
            int row = row0 + rt * 16 + (lane >> 4) * 4 + reg;
            if (row < N) {
                float v[4];
                float ss = 0.f;
                #pragma unroll
                for (int ct = 0; ct < 4; ct++) {
                    v[ct] = acc[rt][ct][reg] + bias[ct];
                    ss += v[ct] * v[ct];
                }
                #pragma unroll
                for (int m = 1; m < 16; m <<= 1) ss += __shfl_xor(ss, m);
                float rn = rsqrtf(fmaxf(ss, 1e-24f));
                float t4[4];
                float mean = 0.f;
                #pragma unroll
                for (int ct = 0; ct < 4; ct++) {
                    float o = fmaxf(v[ct] * rn, 0.f);
                    float hres = bf2f(hin[(size_t)row * HID + ct * 16 + (lane & 15)]);
                    t4[ct] = o + hres;
                    mean += t4[ct];
                }
                #pragma unroll
                for (int m = 1; m < 16; m <<= 1) mean += __shfl_xor(mean, m);
                mean *= (1.f / 64.f);
                float var = 0.f;
                #pragma unroll
                for (int ct = 0; ct < 4; ct++) {
                    float d = t4[ct] - mean;
                    var += d * d;
                }
                #pragma unroll
                for (int m = 1; m < 16; m <<= 1) var += __shfl_xor(var, m);
                var *= (1.f / 64.f);
                float rv = rsqrtf(var + 1e-5f);
                if (!LAST) {
                    #pragma unroll
                    for (int ct = 0; ct < 4; ct++)
                        hout[(size_t)row * HID + ct * 16 + (lane & 15)] =
                            f2bf((t4[ct] - mean) * rv * g4[ct] + be4[ct]);
                } else {
                    // second (output) layer norm, fused; write f32
                    float y[4];
                    float m2 = 0.f;
                    #pragma unroll
                    for (int ct = 0; ct < 4; ct++) {
                        y[ct] = (t4[ct] - mean) * rv * g4[ct] + be4[ct];
                        m2 += y[ct];
                    }
                    #pragma unroll
                    for (int m = 1; m < 16; m <<= 1) m2 += __shfl_xor(m2, m);
                    m2 *= (1.f / 64.f);
                    float v2 = 0.f;
                    #pragma unroll
                    for (int ct = 0; ct < 4; ct++) {
                        float d = y[ct] - m2;
                        v2 += d * d;
                    }
                    #pragma unroll
                    for (int m = 1; m < 16; m <<= 1) v2 += __shfl_xor(v2, m);
                    v2 *= (1.f / 64.f);
                    float rv2 = rsqrtf(v2 + 1e-5f);
                    #pragma unroll
                    for (int ct = 0; ct < 4; ct++)
                        fout[(size_t)row * HID + ct * 16 + (lane & 15)] =
                            (y[ct] - m2) * rv2 * og4[ct] + ob4[ct];
                }
            }
        }
    }
}

extern "C" void kernel_launch(void* const* d_in, const int* in_sizes, int n_in,
                              void* d_out, int out_size, void* d_ws, size_t ws_size,
                              hipStream_t stream) {
    const float* x     = (const float*)d_in[0];
    const int*   ei    = (const int*)d_in[1];
    const float* W_in  = (const float*)d_in[2];
    const float* b_in  = (const float*)d_in[3];
    const float* Wl    = (const float*)d_in[4];
    const float* bl    = (const float*)d_in[5];
    const float* Wr    = (const float*)d_in[6];
    const float* ln_g  = (const float*)d_in[7];
    const float* ln_b  = (const float*)d_in[8];
    const float* out_g = (const float*)d_in[9];
    const float* out_b = (const float*)d_in[10];

    const int N = in_sizes[0] / D_IN;
    const int E = in_sizes[1] / 2;
    const int* src = ei;
    const int* dst = ei + E;
    const int nbuk = (N + BKT_SIZE - 1) >> BKT_BITS;   // 196, must be <= 256

    char* ws = (char*)d_ws;
    size_t off = 0;
    auto take = [&](size_t bytes) {
        char* p = ws + off;
        off += (bytes + 255) & ~(size_t)255;
        return (void*)p;
    };
    u16*      h0      = (u16*)take((size_t)N * HID * 2);
    u16*      h1      = (u16*)take((size_t)N * HID * 2);
    u16*      aggb    = (u16*)take((size_t)N * HID * 2);
    int*      offs    = (int*)take((size_t)(N + 1) * 4);
    float*    rdeg    = (float*)take((size_t)N * 4);
    int*      ssorted = (int*)take((size_t)E * 4);
    unsigned* packedA = (unsigned*)take((size_t)E * 4);
    int*      bcnt    = (int*)take((size_t)nbuk * 4);
    int*      base    = (int*)take((size_t)(nbuk + 1) * 4);
    int*      curA    = (int*)take((size_t)nbuk * 4);

    const int NBLK = (N + 255) / 256;

    // 1) input projection (also zeroes bcnt for step 2)
    proj_mfma<<<NBLK, 256, 0, stream>>>(x, W_in, b_in, h0, N, bcnt, nbuk);

    // 2) CSR build (two-phase binned counting sort)
    bucket_count<<<256, 256, 0, stream>>>(dst, E, bcnt, nbuk);
    bucket_scan<<<1, 256, 0, stream>>>(bcnt, nbuk, base, curA);
    phaseA<<<(E + CHUNK - 1) / CHUNK, 256, 0, stream>>>(src, dst, E, curA, packedA, nbuk);
    phaseB<<<nbuk, 256, 0, stream>>>(packedA, base, N, E, ssorted, offs, rdeg);

    // 3) layers (h0 -> h1 -> h0 -> d_out)
    u16* hc = h0;
    u16* hn = h1;
    for (int l = 0; l < NLAYERS; l++) {
        agg_kernel<<<2048, 256, 0, stream>>>(hc, offs, ssorted, rdeg, aggb, N);
        const float* wl = Wl + (size_t)l * HID * HID;
        const float* wr = Wr + (size_t)l * HID * HID;
        const float* bb = bl + (size_t)l * HID;
        const float* lg = ln_g + (size_t)l * HID;
        const float* lb = ln_b + (size_t)l * HID;
        if (l == NLAYERS - 1) {
            layer_mfma<true><<<NBLK, 256, 0, stream>>>(hc, aggb, wl, wr, bb, lg, lb,
                                                       out_g, out_b, nullptr,
                                                       (float*)d_out, N);
        } else {
            layer_mfma<false><<<NBLK, 256, 0, stream>>>(hc, aggb, wl, wr, bb, lg, lb,
                                                        nullptr, nullptr, hn, nullptr, N);
            u16* tmp = hc; hc = hn; hn = tmp;
        }
    }
}